// Round 6
// baseline (2287.787 us; speedup 1.0000x reference)
//
#include <hip/hip_runtime.h>
#include <hip/hip_bf16.h>

#define NN 50000
#define EE 800000
#define HH 128
#define BB 256
#define CLS 10
#define MLPH 64

#define NBUK 782          // ceil(NN/64) buckets of 64 nodes (dst>>6)
#define EPB 10240         // edges per binning block (40/thread)
#define NBLK_BIN 79       // ceil(EE/EPB)
#define SCAN_N (NBUK * NBLK_BIN)   // 61778
#define SCAN_BLKS 242     // ceil(SCAN_N/256)

typedef __attribute__((ext_vector_type(8))) short short8;
typedef __attribute__((ext_vector_type(4))) float floatx4;

__device__ __forceinline__ float bflo(unsigned u){ unsigned v = u << 16; return __builtin_bit_cast(float, v); }
__device__ __forceinline__ float bfhi(unsigned u){ unsigned v = u & 0xffff0000u; return __builtin_bit_cast(float, v); }
__device__ __forceinline__ unsigned short f2bf(float f){
  unsigned u = __builtin_bit_cast(unsigned, f);
  u += 0x7fffu + ((u >> 16) & 1u);
  return (unsigned short)(u >> 16);
}
__device__ __forceinline__ unsigned pack2(float a, float b){
  return (unsigned)f2bf(a) | ((unsigned)f2bf(b) << 16);
}

// ---------------- init (BN accumulators only) ----------------
__global__ __launch_bounds__(256) void init_k(float* bnsum, float* bnsqs){
  int i = threadIdx.x;
  if (i < HH) { bnsum[i] = 0.0f; bnsqs[i] = 0.0f; }
}

// ---------------- binning pass 1: per-block histogram by dst>>6 (LDS atomics only) ----------------
__global__ __launch_bounds__(256) void bin_count_k(const int* __restrict__ dst, int* __restrict__ cnts){
  __shared__ int hist[NBUK];
  int t = threadIdx.x, blk = blockIdx.x;
  for (int i = t; i < NBUK; i += 256) hist[i] = 0;
  __syncthreads();
  int e0 = blk * EPB;
  #pragma unroll 4
  for (int i = 0; i < EPB / 256; ++i){
    int e = e0 + i * 256 + t;
    if (e < EE) atomicAdd(&hist[dst[e] >> 6], 1);
  }
  __syncthreads();
  for (int u = t; u < NBUK; u += 256) cnts[u * NBLK_BIN + blk] = hist[u];   // bucket-major
}

// ---------------- hierarchical exclusive scan over cnts[SCAN_N] (in place) ----------------
__global__ __launch_bounds__(256) void scanA_k(int* data, int* bsum){
  __shared__ int sd[256];
  int t = threadIdx.x;
  int i = blockIdx.x * 256 + t;
  int v = (i < SCAN_N) ? data[i] : 0;
  sd[t] = v; __syncthreads();
  for (int off = 1; off < 256; off <<= 1){
    int add = (t >= off) ? sd[t - off] : 0;
    __syncthreads();
    sd[t] += add;
    __syncthreads();
  }
  if (i < SCAN_N) data[i] = sd[t] - v;     // exclusive within block
  if (t == 255) bsum[blockIdx.x] = sd[255];
}
__global__ __launch_bounds__(256) void scanB_k(int* bsum){
  __shared__ int sd[256];
  int t = threadIdx.x;
  int v = (t < SCAN_BLKS) ? bsum[t] : 0;
  sd[t] = v; __syncthreads();
  for (int off = 1; off < 256; off <<= 1){
    int add = (t >= off) ? sd[t - off] : 0;
    __syncthreads();
    sd[t] += add;
    __syncthreads();
  }
  if (t < SCAN_BLKS) bsum[t] = sd[t] - v;
}
__global__ __launch_bounds__(256) void scanC_k(int* data, const int* bsum){
  int i = blockIdx.x * 256 + threadIdx.x;
  if (i < SCAN_N) data[i] += bsum[i >> 8];
}

// ---------------- binning pass 2: rank-based scatter, zero global atomics ----------------
// record: x = src | ((dst&63)<<16)   (src<50000 fits 16 bits), y = bits(ew)
__global__ __launch_bounds__(256) void bin_scatter_k(const int* __restrict__ src, const int* __restrict__ dst,
                                                     const float* __restrict__ ew,
                                                     const int* __restrict__ sc, int2* __restrict__ ebin){
  __shared__ int hist[NBUK];
  int t = threadIdx.x, blk = blockIdx.x;
  for (int i = t; i < NBUK; i += 256) hist[i] = 0;
  __syncthreads();
  int e0 = blk * EPB;
  for (int i = 0; i < EPB / 256; ++i){
    int e = e0 + i * 256 + t;
    if (e < EE){
      int d = dst[e];
      int u = d >> 6;
      int r = atomicAdd(&hist[u], 1);
      int pos = sc[u * NBLK_BIN + blk] + r;
      int2 rec; rec.x = src[e] | ((d & 63) << 16); rec.y = __builtin_bit_cast(int, ew[e]);
      ebin[pos] = rec;
    }
  }
}

// ---------------- degree -> dinv, per-bucket LDS accumulation ----------------
__global__ __launch_bounds__(256) void deg_bin_k(const int2* __restrict__ ebin, const int* __restrict__ sc,
                                                 float* __restrict__ dinv){
  __shared__ float dacc[64];
  int t = threadIdx.x, u = blockIdx.x;
  if (t < 64) dacc[t] = 0.0f;
  __syncthreads();
  int start = sc[u * NBLK_BIN], end = (u + 1 < NBUK) ? sc[(u + 1) * NBLK_BIN] : EE;
  for (int e = start + t; e < end; e += 256){
    int2 rec = ebin[e];
    atomicAdd(&dacc[rec.x >> 16], __builtin_bit_cast(float, rec.y));
  }
  __syncthreads();
  if (t < 64){
    int n = u * 64 + t;
    if (n < NN) dinv[n] = rsqrtf(1.0f + dacc[t]);   // self-loop weight 1
  }
}

// ---------------- graph boundaries: gstart[b] = lower_bound(batch, b) ----------------
__global__ __launch_bounds__(256) void gbounds_k(const int* __restrict__ batch, int* gstart){
  int b = threadIdx.x;
  int lo = 0, hi = NN;
  while (lo < hi){
    int mid = (lo + hi) >> 1;
    if (batch[mid] < b) lo = mid + 1; else hi = mid;
  }
  gstart[b] = lo;
  if (b == 0) gstart[BB] = NN;
}

// ---------------- x (f32) -> bf16 packed ----------------
__global__ __launch_bounds__(256) void cvt_x_k(const float* __restrict__ x, unsigned* __restrict__ xb){
  int i = blockIdx.x * 256 + threadIdx.x;
  if (i >= NN * HH / 2) return;
  float2 v = ((const float2*)x)[i];
  xb[i] = pack2(v.x, v.y);
}

// ---------------- W1/W2/W3 (f32, [k][n]) -> Wt bf16 [n][k] ----------------
__global__ __launch_bounds__(256) void transpose3_k(const float* W1, const float* W2, const float* W3,
                                                    unsigned short* Wt1, unsigned short* Wt2, unsigned short* Wt3){
  int gi = blockIdx.x * 256 + threadIdx.x;
  int w = gi >> 14;
  int i = gi & 16383;
  const float* W = (w == 0) ? W1 : (w == 1) ? W2 : W3;
  unsigned short* Wt = (w == 0) ? Wt1 : (w == 1) ? Wt2 : Wt3;
  int n = i >> 7, k = i & 127;
  Wt[i] = f2bf(W[(k << 7) + n]);
}

// ---------------- GEMM: G = dinv[m] * (X[M,128] @ W[128,128]) ----------------
// Operand-swapped MFMA: A = Wt (LDS), B = X rows (global). D: row=channel, col=node.
// Lane thus owns 4 consecutive channels of one node -> 8B packed stores.
__global__ __launch_bounds__(256) void gemm128_k(const unsigned short* __restrict__ X,
                                                 const unsigned short* __restrict__ Wt,
                                                 const float* __restrict__ dinv,
                                                 unsigned short* __restrict__ Gout, int nrows){
  __shared__ __align__(16) unsigned short lw[HH * 136];
  {
    const float4* s4 = (const float4*)Wt;
    float4* d4 = (float4*)lw;
    for (int i = threadIdx.x; i < 2048; i += 256){
      int row = i >> 4, off = i & 15;
      d4[row * 17 + off] = s4[i];
    }
  }
  __syncthreads();
  int wave = threadIdx.x >> 6;
  int lane = threadIdx.x & 63;
  int r16 = lane & 15, quad = lane >> 4;
  int m0 = blockIdx.x * 128 + wave * 32;

  short8 xfrag[2][4];
  float dv[2];
  for (int nt = 0; nt < 2; ++nt){
    int m = m0 + nt * 16 + r16;
    int msafe = (m < nrows) ? m : 0;
    const short8* xrow = (const short8*)(X + (size_t)msafe * HH);
    for (int kk = 0; kk < 4; ++kk) xfrag[nt][kk] = xrow[4 * kk + quad];
    dv[nt] = (m < nrows) ? dinv[m] : 0.0f;
  }
  for (int ct = 0; ct < 8; ++ct){
    floatx4 acc0 = {0.f,0.f,0.f,0.f}, acc1 = {0.f,0.f,0.f,0.f};
    const short8* wrow = (const short8*)(lw + (16 * ct + r16) * 136);
    for (int kk = 0; kk < 4; ++kk){
      short8 wfrag = wrow[4 * kk + quad];
      acc0 = __builtin_amdgcn_mfma_f32_16x16x32_bf16(wfrag, xfrag[0][kk], acc0, 0, 0, 0);
      acc1 = __builtin_amdgcn_mfma_f32_16x16x32_bf16(wfrag, xfrag[1][kk], acc1, 0, 0, 0);
    }
    int ch0 = ct * 16 + quad * 4;          // D: col=lane&15 (node), row=quad*4+r (channel)
    int m = m0 + r16;
    if (m < nrows){
      uint2 pk; pk.x = pack2(acc0[0] * dv[0], acc0[1] * dv[0]);
      pk.y = pack2(acc0[2] * dv[0], acc0[3] * dv[0]);
      ((uint2*)Gout)[((size_t)m * HH + ch0) >> 2] = pk;
    }
    int m2 = m0 + 16 + r16;
    if (m2 < nrows){
      uint2 pk; pk.x = pack2(acc1[0] * dv[1], acc1[1] * dv[1]);
      pk.y = pack2(acc1[2] * dv[1], acc1[3] * dv[1]);
      ((uint2*)Gout)[((size_t)m2 * HH + ch0) >> 2] = pk;
    }
  }
}

// ---------------- aggregation: edge-parallel, LDS fp32 accumulators per 64-node bucket ----------------
// out[d] = relu(dinv[d]*(sum ew*G[s] + G[d]) + bias),  G = dinv*(X@W)
__global__ __launch_bounds__(256) void agg_bin_k(const unsigned short* __restrict__ Gin,
                                                 const int2* __restrict__ ebin,
                                                 const int* __restrict__ sc,
                                                 const float* __restrict__ dinv,
                                                 const float* __restrict__ bias,
                                                 unsigned short* __restrict__ Xout){
  __shared__ float acc[64 * HH];           // 32 KB
  int t = threadIdx.x, u = blockIdx.x;
  int wv = t >> 6, lane = t & 63;
  for (int i = t; i < 64 * HH; i += 256) acc[i] = 0.0f;
  __syncthreads();
  int start = sc[u * NBLK_BIN], end = (u + 1 < NBUK) ? sc[(u + 1) * NBLK_BIN] : EE;
  const unsigned* G = (const unsigned*)Gin;
  for (int e = start + wv; e < end; e += 4){
    int2 rec = ebin[e];
    int s = rec.x & 0xFFFF;
    int dl = rec.x >> 16;
    float w = __builtin_bit_cast(float, rec.y);
    unsigned g = G[(size_t)s * 64 + lane];
    atomicAdd(&acc[dl * HH + 2 * lane],     w * bflo(g));
    atomicAdd(&acc[dl * HH + 2 * lane + 1], w * bfhi(g));
  }
  __syncthreads();
  float2 bb = ((const float2*)bias)[lane];
  for (int i = wv; i < 64; i += 4){
    int n = u * 64 + i;
    if (n >= NN) continue;
    unsigned g = G[(size_t)n * 64 + lane];
    float a0 = acc[i * HH + 2 * lane]     + bflo(g);
    float a1 = acc[i * HH + 2 * lane + 1] + bfhi(g);
    float di = dinv[n];
    a0 = fmaxf(fmaf(di, a0, bb.x), 0.0f);
    a1 = fmaxf(fmaf(di, a1, bb.y), 0.0f);
    ((unsigned*)Xout)[(size_t)n * 64 + lane] = pack2(a0, a1);
  }
}

// ---------------- pooling + BN stats: one block per graph (batch sorted) ----------------
__global__ __launch_bounds__(256) void pool_k(const unsigned short* __restrict__ H3,
                                              const int* __restrict__ gstart,
                                              float* __restrict__ S, float* bnsum, float* bnsqs,
                                              float* cntf){
  __shared__ float rs0[256], rs1[256], rq0[256], rq1[256];
  int b = blockIdx.x;
  int t = threadIdx.x, colc = t & 63, sub = t >> 6;
  int start = gstart[b], end = gstart[b + 1];
  const unsigned* Hrow = (const unsigned*)H3;
  float s0 = 0, s1 = 0, q0 = 0, q1 = 0;
  #pragma unroll 4
  for (int n = start + sub; n < end; n += 4){
    unsigned h = Hrow[(size_t)n * 64 + colc];
    float a = bflo(h), c = bfhi(h);
    s0 += a; s1 += c; q0 += a * a; q1 += c * c;
  }
  rs0[t] = s0; rs1[t] = s1; rq0[t] = q0; rq1[t] = q1;
  __syncthreads();
  if (sub == 0){
    float t0 = rs0[colc] + rs0[colc + 64] + rs0[colc + 128] + rs0[colc + 192];
    float t1 = rs1[colc] + rs1[colc + 64] + rs1[colc + 128] + rs1[colc + 192];
    float u0 = rq0[colc] + rq0[colc + 64] + rq0[colc + 128] + rq0[colc + 192];
    float u1 = rq1[colc] + rq1[colc + 64] + rq1[colc + 128] + rq1[colc + 192];
    S[b * HH + 2 * colc]     = t0;
    S[b * HH + 2 * colc + 1] = t1;
    atomicAdd(&bnsum[2 * colc], t0);
    atomicAdd(&bnsum[2 * colc + 1], t1);
    atomicAdd(&bnsqs[2 * colc], u0);
    atomicAdd(&bnsqs[2 * colc + 1], u1);
    if (t == 0) cntf[b] = (float)(end - start);
  }
}

// ---------------- BN affine on pooled means + MLP head (f32 out) ----------------
__global__ __launch_bounds__(64) void mlp_head_k(const float* __restrict__ S, const float* __restrict__ cntf,
                                                 const float* __restrict__ bnsum, const float* __restrict__ bnsqs,
                                                 const float* gamma, const float* beta,
                                                 const float* Wm1, const float* bm1,
                                                 const float* Wm2, const float* bm2,
                                                 float* out){
  __shared__ float gb[HH];
  __shared__ float t[MLPH];
  int b = blockIdx.x, j = threadIdx.x;
  float inv = 1.0f / fmaxf(cntf[b], 1.0f);
  for (int c = j; c < HH; c += 64){
    float mu = bnsum[c] * (1.0f / NN);
    float var = bnsqs[c] * (1.0f / NN) - mu * mu;
    float istd = rsqrtf(var + 1e-5f);
    float g = S[b * HH + c] * inv;
    gb[c] = (g - mu) * istd * gamma[c] + beta[c];
  }
  __syncthreads();
  float acc = bm1[j];
  for (int k = 0; k < HH; ++k) acc = fmaf(gb[k], Wm1[k * MLPH + j], acc);
  t[j] = acc;
  __syncthreads();
  if (j < CLS){
    float o = bm2[j];
    for (int k = 0; k < MLPH; ++k) o = fmaf(t[k], Wm2[k * CLS + j], o);
    out[b * CLS + j] = o;
  }
}

static inline size_t al(size_t x){ return (x + 255) & ~(size_t)255; }

extern "C" void kernel_launch(void* const* d_in, const int* in_sizes, int n_in,
                              void* d_out, int out_size, void* d_ws, size_t ws_size,
                              hipStream_t stream){
  const float* x     = (const float*)d_in[0];
  const int*   ei    = (const int*)d_in[1];          // [2][E]: src, dst
  const float* ea    = (const float*)d_in[2];
  const int*   batch = (const int*)d_in[3];
  const float* W1 = (const float*)d_in[4];
  const float* b1 = (const float*)d_in[5];
  const float* W2 = (const float*)d_in[6];
  const float* b2 = (const float*)d_in[7];
  const float* W3 = (const float*)d_in[8];
  const float* b3 = (const float*)d_in[9];
  const float* gamma = (const float*)d_in[10];
  const float* beta  = (const float*)d_in[11];
  const float* Wm1 = (const float*)d_in[12];
  const float* bm1 = (const float*)d_in[13];
  const float* Wm2 = (const float*)d_in[14];
  const float* bm2 = (const float*)d_in[15];
  const int* srcv = ei;
  const int* dstv = ei + EE;

  char* p = (char*)d_ws;
  float* dinv   = (float*)p;            p += al(NN * 4);
  int*   cnts   = (int*)p;              p += al((size_t)SCAN_N * 4);
  int*   bsum   = (int*)p;              p += al(SCAN_BLKS * 4);
  int*   gstart = (int*)p;              p += al((BB + 1) * 4);
  int2*  ebin   = (int2*)p;             p += al((size_t)EE * 8);
  unsigned short* Wt1  = (unsigned short*)p; p += al(HH * HH * 2);
  unsigned short* Wt2  = (unsigned short*)p; p += al(HH * HH * 2);
  unsigned short* Wt3  = (unsigned short*)p; p += al(HH * HH * 2);
  unsigned short* bufA = (unsigned short*)p; p += al((size_t)NN * HH * 2);
  unsigned short* bufB = (unsigned short*)p; p += al((size_t)NN * HH * 2);
  float* S     = (float*)p;             p += al(BB * HH * 4);
  float* bnsum = (float*)p;             p += al(HH * 4);
  float* bnsqs = (float*)p;             p += al(HH * 4);
  float* cntf  = (float*)p;             p += al(BB * 4);

  const int nT = 256;

  init_k<<<dim3(1), nT, 0, stream>>>(bnsum, bnsqs);
  bin_count_k<<<dim3(NBLK_BIN), nT, 0, stream>>>(dstv, cnts);
  scanA_k<<<dim3(SCAN_BLKS), nT, 0, stream>>>(cnts, bsum);
  scanB_k<<<dim3(1), nT, 0, stream>>>(bsum);
  scanC_k<<<dim3(SCAN_BLKS), nT, 0, stream>>>(cnts, bsum);
  bin_scatter_k<<<dim3(NBLK_BIN), nT, 0, stream>>>(srcv, dstv, ea, cnts, ebin);
  deg_bin_k<<<dim3(NBUK), nT, 0, stream>>>(ebin, cnts, dinv);
  gbounds_k<<<dim3(1), nT, 0, stream>>>(batch, gstart);
  cvt_x_k<<<dim3((NN * HH / 2 + 255) / 256), nT, 0, stream>>>(x, (unsigned*)bufB);
  transpose3_k<<<dim3(192), nT, 0, stream>>>(W1, W2, W3, Wt1, Wt2, Wt3);

  dim3 gGemm((NN + 127) / 128), gAgg(NBUK);
  // layer 1:  bufB(x) -> bufA(G1) -> bufB(X2)
  gemm128_k<<<gGemm, nT, 0, stream>>>(bufB, Wt1, dinv, bufA, NN);
  agg_bin_k<<<gAgg, nT, 0, stream>>>(bufA, ebin, cnts, dinv, b1, bufB);
  // layer 2
  gemm128_k<<<gGemm, nT, 0, stream>>>(bufB, Wt2, dinv, bufA, NN);
  agg_bin_k<<<gAgg, nT, 0, stream>>>(bufA, ebin, cnts, dinv, b2, bufB);
  // layer 3
  gemm128_k<<<gGemm, nT, 0, stream>>>(bufB, Wt3, dinv, bufA, NN);
  agg_bin_k<<<gAgg, nT, 0, stream>>>(bufA, ebin, cnts, dinv, b3, bufB);

  pool_k<<<dim3(BB), nT, 0, stream>>>(bufB, gstart, S, bnsum, bnsqs, cntf);
  mlp_head_k<<<dim3(BB), dim3(64), 0, stream>>>(S, cntf, bnsum, bnsqs, gamma, beta,
                                                Wm1, bm1, Wm2, bm2, (float*)d_out);
}

// Round 7
// 324.225 us; speedup vs baseline: 7.0562x; 7.0562x over previous
//
#include <hip/hip_runtime.h>
#include <hip/hip_bf16.h>

#define NN 50000
#define EE 800000
#define HH 128
#define BB 256
#define CLS 10
#define MLPH 64
#define CAP 64          // bucket capacity per node (max degree; Poisson(16) tail << 64)

typedef __attribute__((ext_vector_type(8))) short short8;
typedef __attribute__((ext_vector_type(4))) float floatx4;

__device__ __forceinline__ float bflo(unsigned u){ unsigned v = u << 16; return __builtin_bit_cast(float, v); }
__device__ __forceinline__ float bfhi(unsigned u){ unsigned v = u & 0xffff0000u; return __builtin_bit_cast(float, v); }
__device__ __forceinline__ unsigned short f2bf(float f){
  unsigned u = __builtin_bit_cast(unsigned, f);
  u += 0x7fffu + ((u >> 16) & 1u);
  return (unsigned short)(u >> 16);
}
__device__ __forceinline__ unsigned pack2(float a, float b){
  return (unsigned)f2bf(a) | ((unsigned)f2bf(b) << 16);
}

// ---------------- init ----------------
__global__ __launch_bounds__(256) void init_k(int* cnt, float* bnsum, float* bnsqs){
  int i = blockIdx.x * 256 + threadIdx.x;
  if (i < NN) cnt[i] = 0;
  if (i < HH) { bnsum[i] = 0.0f; bnsqs[i] = 0.0f; }
}

// ---------------- bucket scatter: 1 atomic + one 8B write per edge ----------------
__global__ __launch_bounds__(256) void scatter_k(const int* __restrict__ src, const int* __restrict__ dst,
                                                 const float* __restrict__ ew,
                                                 int* __restrict__ cnt, int2* __restrict__ ebuf){
  int e = blockIdx.x * 256 + threadIdx.x;
  if (e >= EE) return;
  int d = dst[e];
  int p = atomicAdd(&cnt[d], 1);
  if (p < CAP){
    int2 rec; rec.x = src[e]; rec.y = __builtin_bit_cast(int, ew[e]);
    ebuf[(size_t)d * CAP + p] = rec;
  }
}

// ---------------- deg -> dinv, per-node wave reduction (no atomics) ----------------
__global__ __launch_bounds__(256) void degdinv_k(const int2* __restrict__ ebuf, const int* __restrict__ cnt,
                                                 float* __restrict__ dinv){
  int node = blockIdx.x * 4 + (threadIdx.x >> 6);
  if (node >= NN) return;
  int lane = threadIdx.x & 63;
  int c = min(cnt[node], CAP);
  float w = 0.0f;
  if (lane < c) w = __builtin_bit_cast(float, ebuf[(size_t)node * CAP + lane].y);
  #pragma unroll
  for (int off = 32; off; off >>= 1) w += __shfl_down(w, off);
  if (lane == 0) dinv[node] = rsqrtf(1.0f + w);   // self-loop weight 1
}

// ---------------- graph boundaries: gstart[b] = lower_bound(batch, b) ----------------
__global__ __launch_bounds__(256) void gbounds_k(const int* __restrict__ batch, int* gstart){
  int b = threadIdx.x;
  int lo = 0, hi = NN;
  while (lo < hi){
    int mid = (lo + hi) >> 1;
    if (batch[mid] < b) lo = mid + 1; else hi = mid;
  }
  gstart[b] = lo;
  if (b == 0) gstart[BB] = NN;
}

// ---------------- x (f32) -> bf16 packed ----------------
__global__ __launch_bounds__(256) void cvt_x_k(const float* __restrict__ x, unsigned* __restrict__ xb){
  int i = blockIdx.x * 256 + threadIdx.x;
  if (i >= NN * HH / 2) return;
  float2 v = ((const float2*)x)[i];
  xb[i] = pack2(v.x, v.y);
}

// ---------------- W1/W2/W3 (f32, [k][n]) -> Wt bf16 [n][k] ----------------
__global__ __launch_bounds__(256) void transpose3_k(const float* W1, const float* W2, const float* W3,
                                                    unsigned short* Wt1, unsigned short* Wt2, unsigned short* Wt3){
  int gi = blockIdx.x * 256 + threadIdx.x;
  int w = gi >> 14;
  int i = gi & 16383;
  const float* W = (w == 0) ? W1 : (w == 1) ? W2 : W3;
  unsigned short* Wt = (w == 0) ? Wt1 : (w == 1) ? Wt2 : Wt3;
  int n = i >> 7, k = i & 127;
  Wt[i] = f2bf(W[(k << 7) + n]);
}

// ---------------- GEMM: G = dinv[m] * (X[M,128] @ W[128,128]) ----------------
// Operand-swapped MFMA (verified R6): A = Wt (LDS), B = X rows. D: row=channel, col=node.
// Lane owns 4 consecutive channels of one node -> 8B packed stores.
__global__ __launch_bounds__(256) void gemm128_k(const unsigned short* __restrict__ X,
                                                 const unsigned short* __restrict__ Wt,
                                                 const float* __restrict__ dinv,
                                                 unsigned short* __restrict__ Gout, int nrows){
  __shared__ __align__(16) unsigned short lw[HH * 136];
  {
    const float4* s4 = (const float4*)Wt;
    float4* d4 = (float4*)lw;
    for (int i = threadIdx.x; i < 2048; i += 256){
      int row = i >> 4, off = i & 15;
      d4[row * 17 + off] = s4[i];
    }
  }
  __syncthreads();
  int wave = threadIdx.x >> 6;
  int lane = threadIdx.x & 63;
  int r16 = lane & 15, quad = lane >> 4;
  int m0 = blockIdx.x * 128 + wave * 32;

  short8 xfrag[2][4];
  float dv[2];
  for (int nt = 0; nt < 2; ++nt){
    int m = m0 + nt * 16 + r16;
    int msafe = (m < nrows) ? m : 0;
    const short8* xrow = (const short8*)(X + (size_t)msafe * HH);
    for (int kk = 0; kk < 4; ++kk) xfrag[nt][kk] = xrow[4 * kk + quad];
    dv[nt] = (m < nrows) ? dinv[m] : 0.0f;
  }
  for (int ct = 0; ct < 8; ++ct){
    floatx4 acc0 = {0.f,0.f,0.f,0.f}, acc1 = {0.f,0.f,0.f,0.f};
    const short8* wrow = (const short8*)(lw + (16 * ct + r16) * 136);
    for (int kk = 0; kk < 4; ++kk){
      short8 wfrag = wrow[4 * kk + quad];
      acc0 = __builtin_amdgcn_mfma_f32_16x16x32_bf16(wfrag, xfrag[0][kk], acc0, 0, 0, 0);
      acc1 = __builtin_amdgcn_mfma_f32_16x16x32_bf16(wfrag, xfrag[1][kk], acc1, 0, 0, 0);
    }
    int ch0 = ct * 16 + quad * 4;
    int m = m0 + r16;
    if (m < nrows){
      uint2 pk; pk.x = pack2(acc0[0] * dv[0], acc0[1] * dv[0]);
      pk.y = pack2(acc0[2] * dv[0], acc0[3] * dv[0]);
      ((uint2*)Gout)[((size_t)m * HH + ch0) >> 2] = pk;
    }
    int m2 = m0 + 16 + r16;
    if (m2 < nrows){
      uint2 pk; pk.x = pack2(acc1[0] * dv[1], acc1[1] * dv[1]);
      pk.y = pack2(acc1[2] * dv[1], acc1[3] * dv[1]);
      ((uint2*)Gout)[((size_t)m2 * HH + ch0) >> 2] = pk;
    }
  }
}

// ---------------- aggregation: wave-per-node, 4 edges/step via 16-lane x 16B gathers ----------------
// out[d] = relu(dinv[d]*(sum ew*G[s] + G[d]) + bias)
__global__ __launch_bounds__(256) void aggregate_k(const unsigned short* __restrict__ Gin,
                                                   const int2* __restrict__ ebuf,
                                                   const int* __restrict__ cnt,
                                                   const float* __restrict__ dinv,
                                                   const float* __restrict__ bias,
                                                   unsigned short* __restrict__ Xout){
  __shared__ float part[4][4][16][8];          // [wave][group][lane16][8ch] = 8 KB
  int wv = threadIdx.x >> 6, lane = threadIdx.x & 63;
  int node = blockIdx.x * 4 + wv;              // NN = 4*12500 exactly: always < NN
  int g = lane >> 4, l = lane & 15;
  int c = min(cnt[node], CAP);
  // preload edge records, one per lane
  int2 rec; rec.x = 0; rec.y = 0;
  if (lane < c) rec = ebuf[(size_t)node * CAP + lane];
  float acc[8] = {0,0,0,0,0,0,0,0};
  const uint4* G4 = (const uint4*)Gin;         // 16 uint4 per 256B row
  int steps = (c + 3) >> 2;
  for (int j = 0; j < steps; ++j){
    int idx = 4 * j + g;
    int sx = __shfl(rec.x, idx);
    float w = __builtin_bit_cast(float, __shfl(rec.y, idx));
    if (idx >= c){ sx = 0; w = 0.0f; }
    uint4 q = G4[(size_t)sx * 16 + l];         // channels [8l, 8l+8)
    acc[0] = fmaf(w, bflo(q.x), acc[0]);
    acc[1] = fmaf(w, bfhi(q.x), acc[1]);
    acc[2] = fmaf(w, bflo(q.y), acc[2]);
    acc[3] = fmaf(w, bfhi(q.y), acc[3]);
    acc[4] = fmaf(w, bflo(q.z), acc[4]);
    acc[5] = fmaf(w, bfhi(q.z), acc[5]);
    acc[6] = fmaf(w, bflo(q.w), acc[6]);
    acc[7] = fmaf(w, bfhi(q.w), acc[7]);
  }
  #pragma unroll
  for (int k = 0; k < 8; ++k) part[wv][g][l][k] = acc[k];
  __syncthreads();
  // combine 4 group partials; lane covers channels 2*lane, 2*lane+1
  int l0 = lane >> 2, k0 = (lane & 3) * 2;
  float a0 = part[wv][0][l0][k0]   + part[wv][1][l0][k0]   + part[wv][2][l0][k0]   + part[wv][3][l0][k0];
  float a1 = part[wv][0][l0][k0+1] + part[wv][1][l0][k0+1] + part[wv][2][l0][k0+1] + part[wv][3][l0][k0+1];
  unsigned gs = ((const unsigned*)Gin)[(size_t)node * 64 + lane];
  a0 += bflo(gs); a1 += bfhi(gs);              // self message G[d]
  float di = dinv[node];
  float2 bb = ((const float2*)bias)[lane];
  a0 = fmaxf(fmaf(di, a0, bb.x), 0.0f);
  a1 = fmaxf(fmaf(di, a1, bb.y), 0.0f);
  ((unsigned*)Xout)[(size_t)node * 64 + lane] = pack2(a0, a1);
}

// ---------------- pooling + BN stats: one block per graph (batch sorted) ----------------
__global__ __launch_bounds__(256) void pool_k(const unsigned short* __restrict__ H3,
                                              const int* __restrict__ gstart,
                                              float* __restrict__ S, float* bnsum, float* bnsqs,
                                              float* cntf){
  __shared__ float rs0[256], rs1[256], rq0[256], rq1[256];
  int b = blockIdx.x;
  int t = threadIdx.x, colc = t & 63, sub = t >> 6;
  int start = gstart[b], end = gstart[b + 1];
  const unsigned* Hrow = (const unsigned*)H3;
  float s0 = 0, s1 = 0, q0 = 0, q1 = 0;
  #pragma unroll 4
  for (int n = start + sub; n < end; n += 4){
    unsigned h = Hrow[(size_t)n * 64 + colc];
    float a = bflo(h), c = bfhi(h);
    s0 += a; s1 += c; q0 += a * a; q1 += c * c;
  }
  rs0[t] = s0; rs1[t] = s1; rq0[t] = q0; rq1[t] = q1;
  __syncthreads();
  if (sub == 0){
    float t0 = rs0[colc] + rs0[colc + 64] + rs0[colc + 128] + rs0[colc + 192];
    float t1 = rs1[colc] + rs1[colc + 64] + rs1[colc + 128] + rs1[colc + 192];
    float u0 = rq0[colc] + rq0[colc + 64] + rq0[colc + 128] + rq0[colc + 192];
    float u1 = rq1[colc] + rq1[colc + 64] + rq1[colc + 128] + rq1[colc + 192];
    S[b * HH + 2 * colc]     = t0;
    S[b * HH + 2 * colc + 1] = t1;
    atomicAdd(&bnsum[2 * colc], t0);
    atomicAdd(&bnsum[2 * colc + 1], t1);
    atomicAdd(&bnsqs[2 * colc], u0);
    atomicAdd(&bnsqs[2 * colc + 1], u1);
    if (t == 0) cntf[b] = (float)(end - start);
  }
}

// ---------------- BN affine on pooled means + MLP head (f32 out) ----------------
__global__ __launch_bounds__(64) void mlp_head_k(const float* __restrict__ S, const float* __restrict__ cntf,
                                                 const float* __restrict__ bnsum, const float* __restrict__ bnsqs,
                                                 const float* gamma, const float* beta,
                                                 const float* Wm1, const float* bm1,
                                                 const float* Wm2, const float* bm2,
                                                 float* out){
  __shared__ float gb[HH];
  __shared__ float t[MLPH];
  int b = blockIdx.x, j = threadIdx.x;
  float inv = 1.0f / fmaxf(cntf[b], 1.0f);
  for (int c = j; c < HH; c += 64){
    float mu = bnsum[c] * (1.0f / NN);
    float var = bnsqs[c] * (1.0f / NN) - mu * mu;
    float istd = rsqrtf(var + 1e-5f);
    float g = S[b * HH + c] * inv;
    gb[c] = (g - mu) * istd * gamma[c] + beta[c];
  }
  __syncthreads();
  float acc = bm1[j];
  for (int k = 0; k < HH; ++k) acc = fmaf(gb[k], Wm1[k * MLPH + j], acc);
  t[j] = acc;
  __syncthreads();
  if (j < CLS){
    float o = bm2[j];
    for (int k = 0; k < MLPH; ++k) o = fmaf(t[k], Wm2[k * CLS + j], o);
    out[b * CLS + j] = o;
  }
}

static inline size_t al(size_t x){ return (x + 255) & ~(size_t)255; }

extern "C" void kernel_launch(void* const* d_in, const int* in_sizes, int n_in,
                              void* d_out, int out_size, void* d_ws, size_t ws_size,
                              hipStream_t stream){
  const float* x     = (const float*)d_in[0];
  const int*   ei    = (const int*)d_in[1];          // [2][E]: src, dst
  const float* ea    = (const float*)d_in[2];
  const int*   batch = (const int*)d_in[3];
  const float* W1 = (const float*)d_in[4];
  const float* b1 = (const float*)d_in[5];
  const float* W2 = (const float*)d_in[6];
  const float* b2 = (const float*)d_in[7];
  const float* W3 = (const float*)d_in[8];
  const float* b3 = (const float*)d_in[9];
  const float* gamma = (const float*)d_in[10];
  const float* beta  = (const float*)d_in[11];
  const float* Wm1 = (const float*)d_in[12];
  const float* bm1 = (const float*)d_in[13];
  const float* Wm2 = (const float*)d_in[14];
  const float* bm2 = (const float*)d_in[15];
  const int* srcv = ei;
  const int* dstv = ei + EE;

  char* p = (char*)d_ws;
  float* dinv   = (float*)p;            p += al(NN * 4);
  int*   cnt    = (int*)p;              p += al(NN * 4);
  int*   gstart = (int*)p;              p += al((BB + 1) * 4);
  int2*  ebuf   = (int2*)p;             p += al((size_t)NN * CAP * 8);
  unsigned short* Wt1  = (unsigned short*)p; p += al(HH * HH * 2);
  unsigned short* Wt2  = (unsigned short*)p; p += al(HH * HH * 2);
  unsigned short* Wt3  = (unsigned short*)p; p += al(HH * HH * 2);
  unsigned short* bufA = (unsigned short*)p; p += al((size_t)NN * HH * 2);
  unsigned short* bufB = (unsigned short*)p; p += al((size_t)NN * HH * 2);
  float* S     = (float*)p;             p += al(BB * HH * 4);
  float* bnsum = (float*)p;             p += al(HH * 4);
  float* bnsqs = (float*)p;             p += al(HH * 4);
  float* cntf  = (float*)p;             p += al(BB * 4);

  const int nT = 256;
  dim3 gN((NN + 255) / 256), gE((EE + 255) / 256), gW((NN + 3) / 4);

  init_k<<<gN, nT, 0, stream>>>(cnt, bnsum, bnsqs);
  scatter_k<<<gE, nT, 0, stream>>>(srcv, dstv, ea, cnt, ebuf);
  degdinv_k<<<gW, nT, 0, stream>>>(ebuf, cnt, dinv);
  gbounds_k<<<dim3(1), nT, 0, stream>>>(batch, gstart);
  cvt_x_k<<<dim3((NN * HH / 2 + 255) / 256), nT, 0, stream>>>(x, (unsigned*)bufB);
  transpose3_k<<<dim3(192), nT, 0, stream>>>(W1, W2, W3, Wt1, Wt2, Wt3);

  dim3 gGemm((NN + 127) / 128);
  // layer 1:  bufB(x) -> bufA(G1) -> bufB(X2)
  gemm128_k<<<gGemm, nT, 0, stream>>>(bufB, Wt1, dinv, bufA, NN);
  aggregate_k<<<gW, nT, 0, stream>>>(bufA, ebuf, cnt, dinv, b1, bufB);
  // layer 2
  gemm128_k<<<gGemm, nT, 0, stream>>>(bufB, Wt2, dinv, bufA, NN);
  aggregate_k<<<gW, nT, 0, stream>>>(bufA, ebuf, cnt, dinv, b2, bufB);
  // layer 3
  gemm128_k<<<gGemm, nT, 0, stream>>>(bufB, Wt3, dinv, bufA, NN);
  aggregate_k<<<gW, nT, 0, stream>>>(bufA, ebuf, cnt, dinv, b3, bufB);

  pool_k<<<dim3(BB), nT, 0, stream>>>(bufB, gstart, S, bnsum, bnsqs, cntf);
  mlp_head_k<<<dim3(BB), dim3(64), 0, stream>>>(S, cntf, bnsum, bnsqs, gamma, beta,
                                                Wm1, bm1, Wm2, bm2, (float*)d_out);
}

// Round 8
// 321.765 us; speedup vs baseline: 7.1101x; 1.0076x over previous
//
#include <hip/hip_runtime.h>
#include <hip/hip_bf16.h>

#define NN 50000
#define EE 800000
#define HH 128
#define BB 256
#define CLS 10
#define MLPH 64
#define CAP 64            // per-node bucket capacity (Poisson(16) max-deg tail << 64)

#define NBUK 782          // ceil(NN/64) coarse buckets (dst>>6)
#define EPB 10240         // edges per binning block
#define NBLK_BIN 79       // ceil(EE/EPB)
#define SCAN_N (NBUK * NBLK_BIN)   // 61778
#define SCAN_BLKS 242     // ceil(SCAN_N/256)

typedef __attribute__((ext_vector_type(8))) short short8;
typedef __attribute__((ext_vector_type(4))) float floatx4;

__device__ __forceinline__ float bflo(unsigned u){ unsigned v = u << 16; return __builtin_bit_cast(float, v); }
__device__ __forceinline__ float bfhi(unsigned u){ unsigned v = u & 0xffff0000u; return __builtin_bit_cast(float, v); }
__device__ __forceinline__ unsigned short f2bf(float f){
  unsigned u = __builtin_bit_cast(unsigned, f);
  u += 0x7fffu + ((u >> 16) & 1u);
  return (unsigned short)(u >> 16);
}
__device__ __forceinline__ unsigned pack2(float a, float b){
  return (unsigned)f2bf(a) | ((unsigned)f2bf(b) << 16);
}

// ---------------- binning pass 1: per-block histogram by dst>>6 (LDS atomics only) ----------------
__global__ __launch_bounds__(256) void bin_count_k(const int* __restrict__ dst, int* __restrict__ cnts){
  __shared__ int hist[NBUK];
  int t = threadIdx.x, blk = blockIdx.x;
  for (int i = t; i < NBUK; i += 256) hist[i] = 0;
  __syncthreads();
  int e0 = blk * EPB;
  #pragma unroll 4
  for (int i = 0; i < EPB / 256; ++i){
    int e = e0 + i * 256 + t;
    if (e < EE) atomicAdd(&hist[dst[e] >> 6], 1);
  }
  __syncthreads();
  for (int u = t; u < NBUK; u += 256) cnts[u * NBLK_BIN + blk] = hist[u];   // bucket-major
}

// ---------------- hierarchical exclusive scan over cnts[SCAN_N] (in place) ----------------
__global__ __launch_bounds__(256) void scanA_k(int* data, int* bsum){
  __shared__ int sd[256];
  int t = threadIdx.x;
  int i = blockIdx.x * 256 + t;
  int v = (i < SCAN_N) ? data[i] : 0;
  sd[t] = v; __syncthreads();
  for (int off = 1; off < 256; off <<= 1){
    int add = (t >= off) ? sd[t - off] : 0;
    __syncthreads();
    sd[t] += add;
    __syncthreads();
  }
  if (i < SCAN_N) data[i] = sd[t] - v;
  if (t == 255) bsum[blockIdx.x] = sd[255];
}
__global__ __launch_bounds__(256) void scanB_k(int* bsum){
  __shared__ int sd[256];
  int t = threadIdx.x;
  int v = (t < SCAN_BLKS) ? bsum[t] : 0;
  sd[t] = v; __syncthreads();
  for (int off = 1; off < 256; off <<= 1){
    int add = (t >= off) ? sd[t - off] : 0;
    __syncthreads();
    sd[t] += add;
    __syncthreads();
  }
  if (t < SCAN_BLKS) bsum[t] = sd[t] - v;
}
__global__ __launch_bounds__(256) void scanC_k(int* data, const int* bsum){
  int i = blockIdx.x * 256 + threadIdx.x;
  if (i < SCAN_N) data[i] += bsum[i >> 8];
}

// ---------------- binning pass 2: rank-based scatter, zero global atomics ----------------
// record: x = src | ((dst&63)<<16)  (src<50000 fits 16 bits), y = bits(ew)
__global__ __launch_bounds__(256) void bin_scatter_k(const int* __restrict__ src, const int* __restrict__ dst,
                                                     const float* __restrict__ ew,
                                                     const int* __restrict__ sc, int2* __restrict__ ebin){
  __shared__ int lbase[NBUK];
  __shared__ int lrank[NBUK];
  int t = threadIdx.x, blk = blockIdx.x;
  for (int i = t; i < NBUK; i += 256){ lbase[i] = sc[i * NBLK_BIN + blk]; lrank[i] = 0; }
  __syncthreads();
  int e0 = blk * EPB;
  for (int i = 0; i < EPB / 256; ++i){
    int e = e0 + i * 256 + t;
    if (e < EE){
      int d = dst[e];
      int u = d >> 6;
      int r = atomicAdd(&lrank[u], 1);
      int2 rec; rec.x = src[e] | ((d & 63) << 16); rec.y = __builtin_bit_cast(int, ew[e]);
      ebin[lbase[u] + r] = rec;
    }
  }
}

// ---------------- binning pass 3: within-bucket sort into per-node CAP slots + cnt + dinv ----------------
__global__ __launch_bounds__(256) void bucket_sort_k(const int2* __restrict__ ebin, const int* __restrict__ sc,
                                                     int2* __restrict__ ebuf, int* __restrict__ cnt,
                                                     float* __restrict__ dinv){
  __shared__ int hist[64];
  __shared__ float wsum[64];
  int t = threadIdx.x, u = blockIdx.x;
  if (t < 64){ hist[t] = 0; wsum[t] = 0.0f; }
  __syncthreads();
  int s0 = sc[u * NBLK_BIN];
  int s1 = (u + 1 < NBUK) ? sc[(u + 1) * NBLK_BIN] : EE;
  for (int e = s0 + t; e < s1; e += 256){
    int2 rec = ebin[e];
    int dl = rec.x >> 16;
    int r = atomicAdd(&hist[dl], 1);
    atomicAdd(&wsum[dl], __builtin_bit_cast(float, rec.y));
    if (r < CAP){
      int2 clean; clean.x = rec.x & 0xFFFF; clean.y = rec.y;
      ebuf[((size_t)(u * 64 + dl)) * CAP + r] = clean;
    }
  }
  __syncthreads();
  if (t < 64){
    int n = u * 64 + t;
    if (n < NN){
      cnt[n] = min(hist[t], CAP);
      dinv[n] = rsqrtf(1.0f + wsum[t]);       // self-loop weight 1
    }
  }
}

// ---------------- graph boundaries + BN accumulator zeroing ----------------
__global__ __launch_bounds__(256) void gbounds_k(const int* __restrict__ batch, int* gstart,
                                                 float* bnsum, float* bnsqs){
  int b = threadIdx.x;
  if (b < HH){ bnsum[b] = 0.0f; bnsqs[b] = 0.0f; }
  int lo = 0, hi = NN;
  while (lo < hi){
    int mid = (lo + hi) >> 1;
    if (batch[mid] < b) lo = mid + 1; else hi = mid;
  }
  gstart[b] = lo;
  if (b == 0) gstart[BB] = NN;
}

// ---------------- W1/W2/W3 (f32, [k][n]) -> Wt bf16 [n][k] ----------------
__global__ __launch_bounds__(256) void transpose3_k(const float* W1, const float* W2, const float* W3,
                                                    unsigned short* Wt1, unsigned short* Wt2, unsigned short* Wt3){
  int gi = blockIdx.x * 256 + threadIdx.x;
  int w = gi >> 14;
  int i = gi & 16383;
  const float* W = (w == 0) ? W1 : (w == 1) ? W2 : W3;
  unsigned short* Wt = (w == 0) ? Wt1 : (w == 1) ? Wt2 : Wt3;
  int n = i >> 7, k = i & 127;
  Wt[i] = f2bf(W[(k << 7) + n]);
}

// ---------------- GEMM (bf16 input): G = dinv[m] * (X[M,128] @ W[128,128]) ----------------
// Operand-swapped MFMA (verified R6/R7): A = Wt (LDS), B = X rows. D: row=channel, col=node.
__global__ __launch_bounds__(256) void gemm128_k(const unsigned short* __restrict__ X,
                                                 const unsigned short* __restrict__ Wt,
                                                 const float* __restrict__ dinv,
                                                 unsigned short* __restrict__ Gout, int nrows){
  __shared__ __align__(16) unsigned short lw[HH * 136];
  {
    const float4* s4 = (const float4*)Wt;
    float4* d4 = (float4*)lw;
    for (int i = threadIdx.x; i < 2048; i += 256){
      int row = i >> 4, off = i & 15;
      d4[row * 17 + off] = s4[i];
    }
  }
  __syncthreads();
  int wave = threadIdx.x >> 6;
  int lane = threadIdx.x & 63;
  int r16 = lane & 15, quad = lane >> 4;
  int m0 = blockIdx.x * 128 + wave * 32;

  short8 xfrag[2][4];
  float dv[2];
  for (int nt = 0; nt < 2; ++nt){
    int m = m0 + nt * 16 + r16;
    int msafe = (m < nrows) ? m : 0;
    const short8* xrow = (const short8*)(X + (size_t)msafe * HH);
    for (int kk = 0; kk < 4; ++kk) xfrag[nt][kk] = xrow[4 * kk + quad];
    dv[nt] = (m < nrows) ? dinv[m] : 0.0f;
  }
  for (int ct = 0; ct < 8; ++ct){
    floatx4 acc0 = {0.f,0.f,0.f,0.f}, acc1 = {0.f,0.f,0.f,0.f};
    const short8* wrow = (const short8*)(lw + (16 * ct + r16) * 136);
    for (int kk = 0; kk < 4; ++kk){
      short8 wfrag = wrow[4 * kk + quad];
      acc0 = __builtin_amdgcn_mfma_f32_16x16x32_bf16(wfrag, xfrag[0][kk], acc0, 0, 0, 0);
      acc1 = __builtin_amdgcn_mfma_f32_16x16x32_bf16(wfrag, xfrag[1][kk], acc1, 0, 0, 0);
    }
    int ch0 = ct * 16 + quad * 4;
    int m = m0 + r16;
    if (m < nrows){
      uint2 pk; pk.x = pack2(acc0[0] * dv[0], acc0[1] * dv[0]);
      pk.y = pack2(acc0[2] * dv[0], acc0[3] * dv[0]);
      ((uint2*)Gout)[((size_t)m * HH + ch0) >> 2] = pk;
    }
    int m2 = m0 + 16 + r16;
    if (m2 < nrows){
      uint2 pk; pk.x = pack2(acc1[0] * dv[1], acc1[1] * dv[1]);
      pk.y = pack2(acc1[2] * dv[1], acc1[3] * dv[1]);
      ((uint2*)Gout)[((size_t)m2 * HH + ch0) >> 2] = pk;
    }
  }
}

// ---------------- GEMM (f32 input, layer 1): converts x in-register (kills cvt_x pass) ----------------
__global__ __launch_bounds__(256) void gemm128_f32_k(const float* __restrict__ X,
                                                     const unsigned short* __restrict__ Wt,
                                                     const float* __restrict__ dinv,
                                                     unsigned short* __restrict__ Gout, int nrows){
  __shared__ __align__(16) unsigned short lw[HH * 136];
  {
    const float4* s4 = (const float4*)Wt;
    float4* d4 = (float4*)lw;
    for (int i = threadIdx.x; i < 2048; i += 256){
      int row = i >> 4, off = i & 15;
      d4[row * 17 + off] = s4[i];
    }
  }
  __syncthreads();
  int wave = threadIdx.x >> 6;
  int lane = threadIdx.x & 63;
  int r16 = lane & 15, quad = lane >> 4;
  int m0 = blockIdx.x * 128 + wave * 32;

  short8 xfrag[2][4];
  float dv[2];
  for (int nt = 0; nt < 2; ++nt){
    int m = m0 + nt * 16 + r16;
    int msafe = (m < nrows) ? m : 0;
    const float4* xr = (const float4*)(X + (size_t)msafe * HH);
    for (int kk = 0; kk < 4; ++kk){
      float4 aA = xr[kk * 8 + quad * 2];
      float4 aB = xr[kk * 8 + quad * 2 + 1];
      uint4 pk;
      pk.x = pack2(aA.x, aA.y); pk.y = pack2(aA.z, aA.w);
      pk.z = pack2(aB.x, aB.y); pk.w = pack2(aB.z, aB.w);
      xfrag[nt][kk] = __builtin_bit_cast(short8, pk);
    }
    dv[nt] = (m < nrows) ? dinv[m] : 0.0f;
  }
  for (int ct = 0; ct < 8; ++ct){
    floatx4 acc0 = {0.f,0.f,0.f,0.f}, acc1 = {0.f,0.f,0.f,0.f};
    const short8* wrow = (const short8*)(lw + (16 * ct + r16) * 136);
    for (int kk = 0; kk < 4; ++kk){
      short8 wfrag = wrow[4 * kk + quad];
      acc0 = __builtin_amdgcn_mfma_f32_16x16x32_bf16(wfrag, xfrag[0][kk], acc0, 0, 0, 0);
      acc1 = __builtin_amdgcn_mfma_f32_16x16x32_bf16(wfrag, xfrag[1][kk], acc1, 0, 0, 0);
    }
    int ch0 = ct * 16 + quad * 4;
    int m = m0 + r16;
    if (m < nrows){
      uint2 pk; pk.x = pack2(acc0[0] * dv[0], acc0[1] * dv[0]);
      pk.y = pack2(acc0[2] * dv[0], acc0[3] * dv[0]);
      ((uint2*)Gout)[((size_t)m * HH + ch0) >> 2] = pk;
    }
    int m2 = m0 + 16 + r16;
    if (m2 < nrows){
      uint2 pk; pk.x = pack2(acc1[0] * dv[1], acc1[1] * dv[1]);
      pk.y = pack2(acc1[2] * dv[1], acc1[3] * dv[1]);
      ((uint2*)Gout)[((size_t)m2 * HH + ch0) >> 2] = pk;
    }
  }
}

// ---------------- aggregation: wave-per-node, 4 edges/step via 16-lane x 16B gathers ----------------
__global__ __launch_bounds__(256) void aggregate_k(const unsigned short* __restrict__ Gin,
                                                   const int2* __restrict__ ebuf,
                                                   const int* __restrict__ cnt,
                                                   const float* __restrict__ dinv,
                                                   const float* __restrict__ bias,
                                                   unsigned short* __restrict__ Xout){
  __shared__ float part[4][4][16][8];          // [wave][group][lane16][8ch] = 8 KB
  int wv = threadIdx.x >> 6, lane = threadIdx.x & 63;
  int node = blockIdx.x * 4 + wv;              // NN = 4*12500 exactly
  int g = lane >> 4, l = lane & 15;
  int c = min(cnt[node], CAP);
  int2 rec; rec.x = 0; rec.y = 0;
  if (lane < c) rec = ebuf[(size_t)node * CAP + lane];
  float acc[8] = {0,0,0,0,0,0,0,0};
  const uint4* G4 = (const uint4*)Gin;
  int steps = (c + 3) >> 2;
  #pragma unroll 2
  for (int j = 0; j < steps; ++j){
    int idx = 4 * j + g;
    int sx = __shfl(rec.x, idx);
    float w = __builtin_bit_cast(float, __shfl(rec.y, idx));
    if (idx >= c){ sx = 0; w = 0.0f; }
    uint4 q = G4[(size_t)sx * 16 + l];
    acc[0] = fmaf(w, bflo(q.x), acc[0]);
    acc[1] = fmaf(w, bfhi(q.x), acc[1]);
    acc[2] = fmaf(w, bflo(q.y), acc[2]);
    acc[3] = fmaf(w, bfhi(q.y), acc[3]);
    acc[4] = fmaf(w, bflo(q.z), acc[4]);
    acc[5] = fmaf(w, bfhi(q.z), acc[5]);
    acc[6] = fmaf(w, bflo(q.w), acc[6]);
    acc[7] = fmaf(w, bfhi(q.w), acc[7]);
  }
  #pragma unroll
  for (int k = 0; k < 8; ++k) part[wv][g][l][k] = acc[k];
  __syncthreads();
  int l0 = lane >> 2, k0 = (lane & 3) * 2;
  float a0 = part[wv][0][l0][k0]   + part[wv][1][l0][k0]   + part[wv][2][l0][k0]   + part[wv][3][l0][k0];
  float a1 = part[wv][0][l0][k0+1] + part[wv][1][l0][k0+1] + part[wv][2][l0][k0+1] + part[wv][3][l0][k0+1];
  unsigned gs = ((const unsigned*)Gin)[(size_t)node * 64 + lane];
  a0 += bflo(gs); a1 += bfhi(gs);
  float di = dinv[node];
  float2 bb = ((const float2*)bias)[lane];
  a0 = fmaxf(fmaf(di, a0, bb.x), 0.0f);
  a1 = fmaxf(fmaf(di, a1, bb.y), 0.0f);
  ((unsigned*)Xout)[(size_t)node * 64 + lane] = pack2(a0, a1);
}

// ---------------- pooling + BN stats: one block per graph (batch sorted) ----------------
__global__ __launch_bounds__(256) void pool_k(const unsigned short* __restrict__ H3,
                                              const int* __restrict__ gstart,
                                              float* __restrict__ S, float* bnsum, float* bnsqs,
                                              float* cntf){
  __shared__ float rs0[256], rs1[256], rq0[256], rq1[256];
  int b = blockIdx.x;
  int t = threadIdx.x, colc = t & 63, sub = t >> 6;
  int start = gstart[b], end = gstart[b + 1];
  const unsigned* Hrow = (const unsigned*)H3;
  float s0 = 0, s1 = 0, q0 = 0, q1 = 0;
  #pragma unroll 4
  for (int n = start + sub; n < end; n += 4){
    unsigned h = Hrow[(size_t)n * 64 + colc];
    float a = bflo(h), c = bfhi(h);
    s0 += a; s1 += c; q0 += a * a; q1 += c * c;
  }
  rs0[t] = s0; rs1[t] = s1; rq0[t] = q0; rq1[t] = q1;
  __syncthreads();
  if (sub == 0){
    float t0 = rs0[colc] + rs0[colc + 64] + rs0[colc + 128] + rs0[colc + 192];
    float t1 = rs1[colc] + rs1[colc + 64] + rs1[colc + 128] + rs1[colc + 192];
    float u0 = rq0[colc] + rq0[colc + 64] + rq0[colc + 128] + rq0[colc + 192];
    float u1 = rq1[colc] + rq1[colc + 64] + rq1[colc + 128] + rq1[colc + 192];
    S[b * HH + 2 * colc]     = t0;
    S[b * HH + 2 * colc + 1] = t1;
    atomicAdd(&bnsum[2 * colc], t0);
    atomicAdd(&bnsum[2 * colc + 1], t1);
    atomicAdd(&bnsqs[2 * colc], u0);
    atomicAdd(&bnsqs[2 * colc + 1], u1);
    if (t == 0) cntf[b] = (float)(end - start);
  }
}

// ---------------- BN affine on pooled means + MLP head (f32 out) ----------------
__global__ __launch_bounds__(64) void mlp_head_k(const float* __restrict__ S, const float* __restrict__ cntf,
                                                 const float* __restrict__ bnsum, const float* __restrict__ bnsqs,
                                                 const float* gamma, const float* beta,
                                                 const float* Wm1, const float* bm1,
                                                 const float* Wm2, const float* bm2,
                                                 float* out){
  __shared__ float gb[HH];
  __shared__ float t[MLPH];
  int b = blockIdx.x, j = threadIdx.x;
  float inv = 1.0f / fmaxf(cntf[b], 1.0f);
  for (int c = j; c < HH; c += 64){
    float mu = bnsum[c] * (1.0f / NN);
    float var = bnsqs[c] * (1.0f / NN) - mu * mu;
    float istd = rsqrtf(var + 1e-5f);
    float g = S[b * HH + c] * inv;
    gb[c] = (g - mu) * istd * gamma[c] + beta[c];
  }
  __syncthreads();
  float acc = bm1[j];
  for (int k = 0; k < HH; ++k) acc = fmaf(gb[k], Wm1[k * MLPH + j], acc);
  t[j] = acc;
  __syncthreads();
  if (j < CLS){
    float o = bm2[j];
    for (int k = 0; k < MLPH; ++k) o = fmaf(t[k], Wm2[k * CLS + j], o);
    out[b * CLS + j] = o;
  }
}

static inline size_t al(size_t x){ return (x + 255) & ~(size_t)255; }

extern "C" void kernel_launch(void* const* d_in, const int* in_sizes, int n_in,
                              void* d_out, int out_size, void* d_ws, size_t ws_size,
                              hipStream_t stream){
  const float* x     = (const float*)d_in[0];
  const int*   ei    = (const int*)d_in[1];          // [2][E]: src, dst
  const float* ea    = (const float*)d_in[2];
  const int*   batch = (const int*)d_in[3];
  const float* W1 = (const float*)d_in[4];
  const float* b1 = (const float*)d_in[5];
  const float* W2 = (const float*)d_in[6];
  const float* b2 = (const float*)d_in[7];
  const float* W3 = (const float*)d_in[8];
  const float* b3 = (const float*)d_in[9];
  const float* gamma = (const float*)d_in[10];
  const float* beta  = (const float*)d_in[11];
  const float* Wm1 = (const float*)d_in[12];
  const float* bm1 = (const float*)d_in[13];
  const float* Wm2 = (const float*)d_in[14];
  const float* bm2 = (const float*)d_in[15];
  const int* srcv = ei;
  const int* dstv = ei + EE;

  char* p = (char*)d_ws;
  float* dinv   = (float*)p;            p += al(NN * 4);
  int*   cnt    = (int*)p;              p += al(NN * 4);
  int*   cnts   = (int*)p;              p += al((size_t)SCAN_N * 4);
  int*   bsum   = (int*)p;              p += al(SCAN_BLKS * 4);
  int*   gstart = (int*)p;              p += al((BB + 1) * 4);
  int2*  ebin   = (int2*)p;             p += al((size_t)EE * 8);
  int2*  ebuf   = (int2*)p;             p += al((size_t)NN * CAP * 8);
  unsigned short* Wt1  = (unsigned short*)p; p += al(HH * HH * 2);
  unsigned short* Wt2  = (unsigned short*)p; p += al(HH * HH * 2);
  unsigned short* Wt3  = (unsigned short*)p; p += al(HH * HH * 2);
  unsigned short* bufA = (unsigned short*)p; p += al((size_t)NN * HH * 2);
  unsigned short* bufB = (unsigned short*)p; p += al((size_t)NN * HH * 2);
  float* S     = (float*)p;             p += al(BB * HH * 4);
  float* bnsum = (float*)p;             p += al(HH * 4);
  float* bnsqs = (float*)p;             p += al(HH * 4);
  float* cntf  = (float*)p;             p += al(BB * 4);

  const int nT = 256;
  dim3 gW((NN + 3) / 4);

  bin_count_k<<<dim3(NBLK_BIN), nT, 0, stream>>>(dstv, cnts);
  scanA_k<<<dim3(SCAN_BLKS), nT, 0, stream>>>(cnts, bsum);
  scanB_k<<<dim3(1), nT, 0, stream>>>(bsum);
  scanC_k<<<dim3(SCAN_BLKS), nT, 0, stream>>>(cnts, bsum);
  bin_scatter_k<<<dim3(NBLK_BIN), nT, 0, stream>>>(srcv, dstv, ea, cnts, ebin);
  bucket_sort_k<<<dim3(NBUK), nT, 0, stream>>>(ebin, cnts, ebuf, cnt, dinv);
  gbounds_k<<<dim3(1), nT, 0, stream>>>(batch, gstart, bnsum, bnsqs);
  transpose3_k<<<dim3(192), nT, 0, stream>>>(W1, W2, W3, Wt1, Wt2, Wt3);

  dim3 gGemm((NN + 127) / 128);
  // layer 1 (f32 x read directly):  x -> bufA(G1) -> bufB(X2)
  gemm128_f32_k<<<gGemm, nT, 0, stream>>>(x, Wt1, dinv, bufA, NN);
  aggregate_k<<<gW, nT, 0, stream>>>(bufA, ebuf, cnt, dinv, b1, bufB);
  // layer 2
  gemm128_k<<<gGemm, nT, 0, stream>>>(bufB, Wt2, dinv, bufA, NN);
  aggregate_k<<<gW, nT, 0, stream>>>(bufA, ebuf, cnt, dinv, b2, bufB);
  // layer 3
  gemm128_k<<<gGemm, nT, 0, stream>>>(bufB, Wt3, dinv, bufA, NN);
  aggregate_k<<<gW, nT, 0, stream>>>(bufA, ebuf, cnt, dinv, b3, bufB);

  pool_k<<<dim3(BB), nT, 0, stream>>>(bufB, gstart, S, bnsum, bnsqs, cntf);
  mlp_head_k<<<dim3(BB), dim3(64), 0, stream>>>(S, cntf, bnsum, bnsqs, gamma, beta,
                                                Wm1, bm1, Wm2, bm2, (float*)d_out);
}

// Round 9
// 286.853 us; speedup vs baseline: 7.9755x; 1.1217x over previous
//
#include <hip/hip_runtime.h>
#include <hip/hip_bf16.h>

#define NN 50000
#define EE 800000
#define HH 128
#define BB 256
#define CLS 10
#define MLPH 64
#define CAP 64            // per-node capacity (max degree; Poisson(16) tail << 64; verified R5-R8)

#define NBUK 196          // ceil(NN/256) coarse buckets (dst>>8), 256 nodes each
#define NBLK 250          // binning blocks
#define EPB 3200          // edges per binning block: 250*3200 = 800000 exactly
#define SCAN_N (NBUK * NBLK)       // 49000
#define SCAN_BLKS 192     // ceil(SCAN_N/256)

typedef __attribute__((ext_vector_type(8))) short short8;
typedef __attribute__((ext_vector_type(4))) float floatx4;

__device__ __forceinline__ float bflo(unsigned u){ unsigned v = u << 16; return __builtin_bit_cast(float, v); }
__device__ __forceinline__ float bfhi(unsigned u){ unsigned v = u & 0xffff0000u; return __builtin_bit_cast(float, v); }
__device__ __forceinline__ unsigned short f2bf(float f){
  unsigned u = __builtin_bit_cast(unsigned, f);
  u += 0x7fffu + ((u >> 16) & 1u);
  return (unsigned short)(u >> 16);
}
__device__ __forceinline__ unsigned pack2(float a, float b){
  return (unsigned)f2bf(a) | ((unsigned)f2bf(b) << 16);
}

// ---------------- binning pass 1: per-block histogram by dst>>8 (LDS atomics only) ----------------
__global__ __launch_bounds__(256) void bin_count_k(const int* __restrict__ dst, int* __restrict__ cnts){
  __shared__ int hist[NBUK];
  int t = threadIdx.x, blk = blockIdx.x;
  if (t < NBUK) hist[t] = 0;
  __syncthreads();
  int e0 = blk * EPB;
  #pragma unroll 4
  for (int i = 0; i < 12; ++i) atomicAdd(&hist[dst[e0 + i * 256 + t] >> 8], 1);
  if (t < 128) atomicAdd(&hist[dst[e0 + 3072 + t] >> 8], 1);
  __syncthreads();
  if (t < NBUK) cnts[t * NBLK + blk] = hist[t];   // bucket-major
}

// ---------------- hierarchical exclusive scan over cnts[SCAN_N] ----------------
__global__ __launch_bounds__(256) void scanA_k(int* data, int* bsum){
  __shared__ int sd[256];
  int t = threadIdx.x;
  int i = blockIdx.x * 256 + t;
  int v = (i < SCAN_N) ? data[i] : 0;
  sd[t] = v; __syncthreads();
  for (int off = 1; off < 256; off <<= 1){
    int add = (t >= off) ? sd[t - off] : 0;
    __syncthreads();
    sd[t] += add;
    __syncthreads();
  }
  if (i < SCAN_N) data[i] = sd[t] - v;          // exclusive within scan-block
  if (t == 255) bsum[blockIdx.x] = sd[255];
}
__global__ __launch_bounds__(256) void scanB_k(int* bsum){
  __shared__ int sd[256];
  int t = threadIdx.x;
  int v = (t < SCAN_BLKS) ? bsum[t] : 0;
  sd[t] = v; __syncthreads();
  for (int off = 1; off < 256; off <<= 1){
    int add = (t >= off) ? sd[t - off] : 0;
    __syncthreads();
    sd[t] += add;
    __syncthreads();
  }
  if (t < SCAN_BLKS) bsum[t] = sd[t] - v;       // exclusive block offsets
}

// ---------------- binning pass 2: rank-based scatter, zero global atomics ----------------
// record: x = src | ((dst&255)<<16)  (src<65536, dst&255<256 -> 24 bits), y = bits(ew)
__global__ __launch_bounds__(256) void bin_scatter_k(const int* __restrict__ src, const int* __restrict__ dst,
                                                     const float* __restrict__ ew,
                                                     const int* __restrict__ sc, const int* __restrict__ bsum,
                                                     int2* __restrict__ ebin){
  __shared__ int lbase[NBUK];
  __shared__ int lrank[NBUK];
  int t = threadIdx.x, blk = blockIdx.x;
  if (t < NBUK){
    int idx = t * NBLK + blk;
    lbase[t] = sc[idx] + bsum[idx >> 8];
    lrank[t] = 0;
  }
  __syncthreads();
  int e0 = blk * EPB;
  for (int i = 0; i < 13; ++i){
    int off = i * 256 + t;
    if (off < EPB){
      int e = e0 + off;
      int d = dst[e];
      int u = d >> 8;
      int r = atomicAdd(&lrank[u], 1);
      int2 rec; rec.x = src[e] | ((d & 255) << 16); rec.y = __builtin_bit_cast(int, ew[e]);
      ebin[lbase[u] + r] = rec;
    }
  }
}

// ---------------- binning pass 3: within-bucket sort into per-node CAP slots + cnt + dinv ----------------
// ebuf record: 4B = src | (bf16(ew) << 16)
__global__ __launch_bounds__(256) void bucket_sort_k(const int2* __restrict__ ebin, const int* __restrict__ sc,
                                                     const int* __restrict__ bsum,
                                                     unsigned* __restrict__ ebuf, int* __restrict__ cnt,
                                                     float* __restrict__ dinv){
  __shared__ int hist[256];
  __shared__ float wsum[256];
  int t = threadIdx.x, u = blockIdx.x;
  hist[t] = 0; wsum[t] = 0.0f;
  __syncthreads();
  int i0 = u * NBLK;
  int s0 = sc[i0] + bsum[i0 >> 8];
  int s1 = EE;
  if (u + 1 < NBUK){ int i1 = (u + 1) * NBLK; s1 = sc[i1] + bsum[i1 >> 8]; }
  for (int e = s0 + t; e < s1; e += 256){
    int2 rec = ebin[e];
    int dl = rec.x >> 16;
    float w = __builtin_bit_cast(float, rec.y);
    int r = atomicAdd(&hist[dl], 1);
    atomicAdd(&wsum[dl], w);
    if (r < CAP){
      unsigned c4 = (unsigned)(rec.x & 0xFFFF) | ((unsigned)f2bf(w) << 16);
      ebuf[((size_t)(u * 256 + dl)) * CAP + r] = c4;
    }
  }
  __syncthreads();
  int n = u * 256 + t;
  if (n < NN){
    cnt[n] = min(hist[t], CAP);
    dinv[n] = rsqrtf(1.0f + wsum[t]);          // self-loop weight 1
  }
}

// ---------------- graph boundaries + BN accumulator zeroing ----------------
__global__ __launch_bounds__(256) void gbounds_k(const int* __restrict__ batch, int* gstart,
                                                 float* bnsum, float* bnsqs){
  int b = threadIdx.x;
  if (b < HH){ bnsum[b] = 0.0f; bnsqs[b] = 0.0f; }
  int lo = 0, hi = NN;
  while (lo < hi){
    int mid = (lo + hi) >> 1;
    if (batch[mid] < b) lo = mid + 1; else hi = mid;
  }
  gstart[b] = lo;
  if (b == 0) gstart[BB] = NN;
}

// ---------------- W1/W2/W3 (f32, [k][n]) -> Wt bf16 [n][k] ----------------
__global__ __launch_bounds__(256) void transpose3_k(const float* W1, const float* W2, const float* W3,
                                                    unsigned short* Wt1, unsigned short* Wt2, unsigned short* Wt3){
  int gi = blockIdx.x * 256 + threadIdx.x;
  int w = gi >> 14;
  int i = gi & 16383;
  const float* W = (w == 0) ? W1 : (w == 1) ? W2 : W3;
  unsigned short* Wt = (w == 0) ? Wt1 : (w == 1) ? Wt2 : Wt3;
  int n = i >> 7, k = i & 127;
  Wt[i] = f2bf(W[(k << 7) + n]);
}

// ---------------- GEMM (bf16 input): G = dinv[m] * (X[M,128] @ W[128,128]) ----------------
__global__ __launch_bounds__(256) void gemm128_k(const unsigned short* __restrict__ X,
                                                 const unsigned short* __restrict__ Wt,
                                                 const float* __restrict__ dinv,
                                                 unsigned short* __restrict__ Gout, int nrows){
  __shared__ __align__(16) unsigned short lw[HH * 136];
  {
    const float4* s4 = (const float4*)Wt;
    float4* d4 = (float4*)lw;
    for (int i = threadIdx.x; i < 2048; i += 256){
      int row = i >> 4, off = i & 15;
      d4[row * 17 + off] = s4[i];
    }
  }
  __syncthreads();
  int wave = threadIdx.x >> 6;
  int lane = threadIdx.x & 63;
  int r16 = lane & 15, quad = lane >> 4;
  int m0 = blockIdx.x * 128 + wave * 32;

  short8 xfrag[2][4];
  float dv[2];
  for (int nt = 0; nt < 2; ++nt){
    int m = m0 + nt * 16 + r16;
    int msafe = (m < nrows) ? m : 0;
    const short8* xrow = (const short8*)(X + (size_t)msafe * HH);
    for (int kk = 0; kk < 4; ++kk) xfrag[nt][kk] = xrow[4 * kk + quad];
    dv[nt] = (m < nrows) ? dinv[m] : 0.0f;
  }
  for (int ct = 0; ct < 8; ++ct){
    floatx4 acc0 = {0.f,0.f,0.f,0.f}, acc1 = {0.f,0.f,0.f,0.f};
    const short8* wrow = (const short8*)(lw + (16 * ct + r16) * 136);
    for (int kk = 0; kk < 4; ++kk){
      short8 wfrag = wrow[4 * kk + quad];
      acc0 = __builtin_amdgcn_mfma_f32_16x16x32_bf16(wfrag, xfrag[0][kk], acc0, 0, 0, 0);
      acc1 = __builtin_amdgcn_mfma_f32_16x16x32_bf16(wfrag, xfrag[1][kk], acc1, 0, 0, 0);
    }
    int ch0 = ct * 16 + quad * 4;
    int m = m0 + r16;
    if (m < nrows){
      uint2 pk; pk.x = pack2(acc0[0] * dv[0], acc0[1] * dv[0]);
      pk.y = pack2(acc0[2] * dv[0], acc0[3] * dv[0]);
      ((uint2*)Gout)[((size_t)m * HH + ch0) >> 2] = pk;
    }
    int m2 = m0 + 16 + r16;
    if (m2 < nrows){
      uint2 pk; pk.x = pack2(acc1[0] * dv[1], acc1[1] * dv[1]);
      pk.y = pack2(acc1[2] * dv[1], acc1[3] * dv[1]);
      ((uint2*)Gout)[((size_t)m2 * HH + ch0) >> 2] = pk;
    }
  }
}

// ---------------- GEMM (f32 input, layer 1): converts x in-register ----------------
__global__ __launch_bounds__(256) void gemm128_f32_k(const float* __restrict__ X,
                                                     const unsigned short* __restrict__ Wt,
                                                     const float* __restrict__ dinv,
                                                     unsigned short* __restrict__ Gout, int nrows){
  __shared__ __align__(16) unsigned short lw[HH * 136];
  {
    const float4* s4 = (const float4*)Wt;
    float4* d4 = (float4*)lw;
    for (int i = threadIdx.x; i < 2048; i += 256){
      int row = i >> 4, off = i & 15;
      d4[row * 17 + off] = s4[i];
    }
  }
  __syncthreads();
  int wave = threadIdx.x >> 6;
  int lane = threadIdx.x & 63;
  int r16 = lane & 15, quad = lane >> 4;
  int m0 = blockIdx.x * 128 + wave * 32;

  short8 xfrag[2][4];
  float dv[2];
  for (int nt = 0; nt < 2; ++nt){
    int m = m0 + nt * 16 + r16;
    int msafe = (m < nrows) ? m : 0;
    const float4* xr = (const float4*)(X + (size_t)msafe * HH);
    for (int kk = 0; kk < 4; ++kk){
      float4 aA = xr[kk * 8 + quad * 2];
      float4 aB = xr[kk * 8 + quad * 2 + 1];
      uint4 pk;
      pk.x = pack2(aA.x, aA.y); pk.y = pack2(aA.z, aA.w);
      pk.z = pack2(aB.x, aB.y); pk.w = pack2(aB.z, aB.w);
      xfrag[nt][kk] = __builtin_bit_cast(short8, pk);
    }
    dv[nt] = (m < nrows) ? dinv[m] : 0.0f;
  }
  for (int ct = 0; ct < 8; ++ct){
    floatx4 acc0 = {0.f,0.f,0.f,0.f}, acc1 = {0.f,0.f,0.f,0.f};
    const short8* wrow = (const short8*)(lw + (16 * ct + r16) * 136);
    for (int kk = 0; kk < 4; ++kk){
      short8 wfrag = wrow[4 * kk + quad];
      acc0 = __builtin_amdgcn_mfma_f32_16x16x32_bf16(wfrag, xfrag[0][kk], acc0, 0, 0, 0);
      acc1 = __builtin_amdgcn_mfma_f32_16x16x32_bf16(wfrag, xfrag[1][kk], acc1, 0, 0, 0);
    }
    int ch0 = ct * 16 + quad * 4;
    int m = m0 + r16;
    if (m < nrows){
      uint2 pk; pk.x = pack2(acc0[0] * dv[0], acc0[1] * dv[0]);
      pk.y = pack2(acc0[2] * dv[0], acc0[3] * dv[0]);
      ((uint2*)Gout)[((size_t)m * HH + ch0) >> 2] = pk;
    }
    int m2 = m0 + 16 + r16;
    if (m2 < nrows){
      uint2 pk; pk.x = pack2(acc1[0] * dv[1], acc1[1] * dv[1]);
      pk.y = pack2(acc1[2] * dv[1], acc1[3] * dv[1]);
      ((uint2*)Gout)[((size_t)m2 * HH + ch0) >> 2] = pk;
    }
  }
}

// ---------------- aggregation: wave-per-node, 4 edges/step via 16-lane x 16B gathers ----------------
__global__ __launch_bounds__(256) void aggregate_k(const unsigned short* __restrict__ Gin,
                                                   const unsigned* __restrict__ ebuf,
                                                   const int* __restrict__ cnt,
                                                   const float* __restrict__ dinv,
                                                   const float* __restrict__ bias,
                                                   unsigned short* __restrict__ Xout){
  __shared__ float part[4][4][16][8];          // [wave][group][lane16][8ch] = 8 KB
  int wv = threadIdx.x >> 6, lane = threadIdx.x & 63;
  int node = blockIdx.x * 4 + wv;              // NN = 4*12500 exactly
  int g = lane >> 4, l = lane & 15;
  int c = min(cnt[node], CAP);
  unsigned rec = 0;                            // src=0, w=+0.0 bf16
  if (lane < c) rec = ebuf[(size_t)node * CAP + lane];
  float acc[8] = {0,0,0,0,0,0,0,0};
  const uint4* G4 = (const uint4*)Gin;
  int steps = (c + 3) >> 2;
  #pragma unroll 4
  for (int j = 0; j < steps; ++j){
    int idx = 4 * j + g;
    unsigned r = (unsigned)__shfl((int)rec, idx);
    int sx = r & 0xFFFF;
    float w = bfhi(r);
    if (idx >= c){ sx = 0; w = 0.0f; }
    uint4 q = G4[(size_t)sx * 16 + l];
    acc[0] = fmaf(w, bflo(q.x), acc[0]);
    acc[1] = fmaf(w, bfhi(q.x), acc[1]);
    acc[2] = fmaf(w, bflo(q.y), acc[2]);
    acc[3] = fmaf(w, bfhi(q.y), acc[3]);
    acc[4] = fmaf(w, bflo(q.z), acc[4]);
    acc[5] = fmaf(w, bfhi(q.z), acc[5]);
    acc[6] = fmaf(w, bflo(q.w), acc[6]);
    acc[7] = fmaf(w, bfhi(q.w), acc[7]);
  }
  #pragma unroll
  for (int k = 0; k < 8; ++k) part[wv][g][l][k] = acc[k];
  __syncthreads();
  int l0 = lane >> 2, k0 = (lane & 3) * 2;
  float a0 = part[wv][0][l0][k0]   + part[wv][1][l0][k0]   + part[wv][2][l0][k0]   + part[wv][3][l0][k0];
  float a1 = part[wv][0][l0][k0+1] + part[wv][1][l0][k0+1] + part[wv][2][l0][k0+1] + part[wv][3][l0][k0+1];
  unsigned gs = ((const unsigned*)Gin)[(size_t)node * 64 + lane];
  a0 += bflo(gs); a1 += bfhi(gs);
  float di = dinv[node];
  float2 bb = ((const float2*)bias)[lane];
  a0 = fmaxf(fmaf(di, a0, bb.x), 0.0f);
  a1 = fmaxf(fmaf(di, a1, bb.y), 0.0f);
  ((unsigned*)Xout)[(size_t)node * 64 + lane] = pack2(a0, a1);
}

// ---------------- pooling + BN stats: one block per graph (batch sorted) ----------------
__global__ __launch_bounds__(256) void pool_k(const unsigned short* __restrict__ H3,
                                              const int* __restrict__ gstart,
                                              float* __restrict__ S, float* bnsum, float* bnsqs,
                                              float* cntf){
  __shared__ float rs0[256], rs1[256], rq0[256], rq1[256];
  int b = blockIdx.x;
  int t = threadIdx.x, colc = t & 63, sub = t >> 6;
  int start = gstart[b], end = gstart[b + 1];
  const unsigned* Hrow = (const unsigned*)H3;
  float s0 = 0, s1 = 0, q0 = 0, q1 = 0;
  #pragma unroll 4
  for (int n = start + sub; n < end; n += 4){
    unsigned h = Hrow[(size_t)n * 64 + colc];
    float a = bflo(h), c = bfhi(h);
    s0 += a; s1 += c; q0 += a * a; q1 += c * c;
  }
  rs0[t] = s0; rs1[t] = s1; rq0[t] = q0; rq1[t] = q1;
  __syncthreads();
  if (sub == 0){
    float t0 = rs0[colc] + rs0[colc + 64] + rs0[colc + 128] + rs0[colc + 192];
    float t1 = rs1[colc] + rs1[colc + 64] + rs1[colc + 128] + rs1[colc + 192];
    float u0 = rq0[colc] + rq0[colc + 64] + rq0[colc + 128] + rq0[colc + 192];
    float u1 = rq1[colc] + rq1[colc + 64] + rq1[colc + 128] + rq1[colc + 192];
    S[b * HH + 2 * colc]     = t0;
    S[b * HH + 2 * colc + 1] = t1;
    atomicAdd(&bnsum[2 * colc], t0);
    atomicAdd(&bnsum[2 * colc + 1], t1);
    atomicAdd(&bnsqs[2 * colc], u0);
    atomicAdd(&bnsqs[2 * colc + 1], u1);
    if (t == 0) cntf[b] = (float)(end - start);
  }
}

// ---------------- BN affine on pooled means + MLP head (f32 out) ----------------
__global__ __launch_bounds__(64) void mlp_head_k(const float* __restrict__ S, const float* __restrict__ cntf,
                                                 const float* __restrict__ bnsum, const float* __restrict__ bnsqs,
                                                 const float* gamma, const float* beta,
                                                 const float* Wm1, const float* bm1,
                                                 const float* Wm2, const float* bm2,
                                                 float* out){
  __shared__ float gb[HH];
  __shared__ float t[MLPH];
  int b = blockIdx.x, j = threadIdx.x;
  float inv = 1.0f / fmaxf(cntf[b], 1.0f);
  for (int c = j; c < HH; c += 64){
    float mu = bnsum[c] * (1.0f / NN);
    float var = bnsqs[c] * (1.0f / NN) - mu * mu;
    float istd = rsqrtf(var + 1e-5f);
    float g = S[b * HH + c] * inv;
    gb[c] = (g - mu) * istd * gamma[c] + beta[c];
  }
  __syncthreads();
  float acc = bm1[j];
  for (int k = 0; k < HH; ++k) acc = fmaf(gb[k], Wm1[k * MLPH + j], acc);
  t[j] = acc;
  __syncthreads();
  if (j < CLS){
    float o = bm2[j];
    for (int k = 0; k < MLPH; ++k) o = fmaf(t[k], Wm2[k * CLS + j], o);
    out[b * CLS + j] = o;
  }
}

static inline size_t al(size_t x){ return (x + 255) & ~(size_t)255; }

extern "C" void kernel_launch(void* const* d_in, const int* in_sizes, int n_in,
                              void* d_out, int out_size, void* d_ws, size_t ws_size,
                              hipStream_t stream){
  const float* x     = (const float*)d_in[0];
  const int*   ei    = (const int*)d_in[1];          // [2][E]: src, dst
  const float* ea    = (const float*)d_in[2];
  const int*   batch = (const int*)d_in[3];
  const float* W1 = (const float*)d_in[4];
  const float* b1 = (const float*)d_in[5];
  const float* W2 = (const float*)d_in[6];
  const float* b2 = (const float*)d_in[7];
  const float* W3 = (const float*)d_in[8];
  const float* b3 = (const float*)d_in[9];
  const float* gamma = (const float*)d_in[10];
  const float* beta  = (const float*)d_in[11];
  const float* Wm1 = (const float*)d_in[12];
  const float* bm1 = (const float*)d_in[13];
  const float* Wm2 = (const float*)d_in[14];
  const float* bm2 = (const float*)d_in[15];
  const int* srcv = ei;
  const int* dstv = ei + EE;

  char* p = (char*)d_ws;
  float* dinv   = (float*)p;            p += al(NN * 4);
  int*   cnt    = (int*)p;              p += al(NN * 4);
  int*   cnts   = (int*)p;              p += al((size_t)SCAN_N * 4);
  int*   bsum   = (int*)p;              p += al(SCAN_BLKS * 4);
  int*   gstart = (int*)p;              p += al((BB + 1) * 4);
  int2*  ebin   = (int2*)p;             p += al((size_t)EE * 8);
  unsigned* ebuf = (unsigned*)p;        p += al((size_t)NN * CAP * 4);
  unsigned short* Wt1  = (unsigned short*)p; p += al(HH * HH * 2);
  unsigned short* Wt2  = (unsigned short*)p; p += al(HH * HH * 2);
  unsigned short* Wt3  = (unsigned short*)p; p += al(HH * HH * 2);
  unsigned short* bufA = (unsigned short*)p; p += al((size_t)NN * HH * 2);
  unsigned short* bufB = (unsigned short*)p; p += al((size_t)NN * HH * 2);
  float* S     = (float*)p;             p += al(BB * HH * 4);
  float* bnsum = (float*)p;             p += al(HH * 4);
  float* bnsqs = (float*)p;             p += al(HH * 4);
  float* cntf  = (float*)p;             p += al(BB * 4);

  const int nT = 256;
  dim3 gW((NN + 3) / 4);

  bin_count_k<<<dim3(NBLK), nT, 0, stream>>>(dstv, cnts);
  scanA_k<<<dim3(SCAN_BLKS), nT, 0, stream>>>(cnts, bsum);
  scanB_k<<<dim3(1), nT, 0, stream>>>(bsum);
  bin_scatter_k<<<dim3(NBLK), nT, 0, stream>>>(srcv, dstv, ea, cnts, bsum, ebin);
  bucket_sort_k<<<dim3(NBUK), nT, 0, stream>>>(ebin, cnts, bsum, ebuf, cnt, dinv);
  gbounds_k<<<dim3(1), nT, 0, stream>>>(batch, gstart, bnsum, bnsqs);
  transpose3_k<<<dim3(192), nT, 0, stream>>>(W1, W2, W3, Wt1, Wt2, Wt3);

  dim3 gGemm((NN + 127) / 128);
  // layer 1 (f32 x read directly):  x -> bufA(G1) -> bufB(X2)
  gemm128_f32_k<<<gGemm, nT, 0, stream>>>(x, Wt1, dinv, bufA, NN);
  aggregate_k<<<gW, nT, 0, stream>>>(bufA, ebuf, cnt, dinv, b1, bufB);
  // layer 2
  gemm128_k<<<gGemm, nT, 0, stream>>>(bufB, Wt2, dinv, bufA, NN);
  aggregate_k<<<gW, nT, 0, stream>>>(bufA, ebuf, cnt, dinv, b2, bufB);
  // layer 3
  gemm128_k<<<gGemm, nT, 0, stream>>>(bufB, Wt3, dinv, bufA, NN);
  aggregate_k<<<gW, nT, 0, stream>>>(bufA, ebuf, cnt, dinv, b3, bufB);

  pool_k<<<dim3(BB), nT, 0, stream>>>(bufB, gstart, S, bnsum, bnsqs, cntf);
  mlp_head_k<<<dim3(BB), dim3(64), 0, stream>>>(S, cntf, bnsum, bnsqs, gamma, beta,
                                                Wm1, bm1, Wm2, bm2, (float*)d_out);
}